// Round 16
// baseline (174.282 us; speedup 1.0000x reference)
//
#include <hip/hip_runtime.h>
#include <hip/hip_bf16.h>
#include <math.h>

// Problem: B=1, N=512, C=256, fp32 in/out.
// out[i,c] = sum_j softmax_j( w[i,j,c] ) * v[j,c],  w = mish(LN(Kp[j]-Qp[i])) @ W2  (+b2 cancels)
// Kp = mish(LN(feat@Wk+bk)) @ W1 + b1 ; Qp = mish(LN(feat@Wq+bq)) @ W1 ; v = feat@Wv+bv
// R16 = R15 (best 124.4us) +
//   1) attn: JT=64 per phase as TWO 32-row subtiles sharing one barrier pair.
//      T = 2 byte-identical copies of the R7-verified 32-row layout (zero layout
//      risk); wv reused across subtiles (#pragma unroll 1 -> no extra liveness,
//      the R11/R14 spill lesson). Barriers/chunk: 16 -> 8.
//   2) repack fused into prep as extra blocks (one fewer launch).

#define N_ 512
#define C_ 256
#define NCHUNK 2
#define JPB (N_ / NCHUNK)   // 256 j's per block
#define JT 64               // j rows per phase (2 subtiles of 32)
#define NT (JPB / JT)       // 4 phases

typedef short s8v __attribute__((ext_vector_type(8)));
typedef short s4v __attribute__((ext_vector_type(4)));
typedef float f4v __attribute__((ext_vector_type(4)));
typedef float f16v __attribute__((ext_vector_type(16)));
typedef unsigned int u4v __attribute__((ext_vector_type(4)));

__device__ __forceinline__ unsigned short f2bf(float x) {
  union { __hip_bfloat16 h; unsigned short u; } cv;
  cv.h = __float2bfloat16(x);
  return cv.u;
}

__device__ __forceinline__ float mish_f(float x) {
  // mish(x) = x*tanh(softplus(x)) = x*(1 - 2/(y^2+1)), y = 1+e^x
  if (x > 25.f) return x;  // tanh saturated to 1.0 in fp32
  float y = 1.f + __expf(x);
  return x - __fdividef(x + x, fmaf(y, y, 1.f));
}

// block (256 thr) reduction of two values, result broadcast to all threads
__device__ __forceinline__ void blockReduce2(float& a, float& b, float* red) {
  #pragma unroll
  for (int m = 1; m < 64; m <<= 1) { a += __shfl_xor(a, m); b += __shfl_xor(b, m); }
  int lane = threadIdx.x & 63, w = threadIdx.x >> 6;
  if (lane == 0) { red[w] = a; red[4 + w] = b; }
  __syncthreads();
  a = red[0] + red[1] + red[2] + red[3];
  b = red[4] + red[5] + red[6] + red[7];
  __syncthreads();
}

// ---------------- prep (blocks 0..255): dist, v, Qp, Kp, stats, bf16 copies
// ---------------- repack (blocks 256..511): W2 -> W2f fragment-linear ----------------
__global__ void __launch_bounds__(256) prep_kernel(
    const float* __restrict__ feat,
    const float* __restrict__ Wq, const float* __restrict__ bq,
    const float* __restrict__ gq, const float* __restrict__ bgq,
    const float* __restrict__ Wk, const float* __restrict__ bk,
    const float* __restrict__ gk, const float* __restrict__ bgk,
    const float* __restrict__ Wv, const float* __restrict__ bv,
    const float* __restrict__ W1, const float* __restrict__ b1,
    const float* __restrict__ W2, unsigned short* __restrict__ W2f,
    float* __restrict__ dist, float* __restrict__ vout,
    float* __restrict__ Qp, float* __restrict__ Kp,
    float* __restrict__ muQ, float* __restrict__ s2Q,
    float* __restrict__ muK, float* __restrict__ s2K,
    unsigned short* __restrict__ Qb, unsigned short* __restrict__ Kb) {
  const int tid = threadIdx.x;

  if (blockIdx.x >= 256) {
    // ---- repack: W2f[((w*16+ks)*64+l)*8+e] = bf16(W2[k][c]),
    //      k = ks*16 + (l>>5)*8 + e, c = w*32 + (l&31) ----
    const int base = (blockIdx.x - 256) * 256 + tid;
    #pragma unroll
    for (int rep = 0; rep < 1; ++rep) {
      int idx = base;  // 65536 total over 256 blocks x 256 thr... need 256 elems/thread? no:
      // 256 blocks x 256 threads = 65536 = exactly one element per thread.
      int e = idx & 7;
      int l = (idx >> 3) & 63;
      int ks = (idx >> 9) & 15;
      int w = idx >> 13;
      int k = ks * 16 + ((l >> 5) << 3) + e;
      int c = (w << 5) + (l & 31);
      W2f[idx] = f2bf(W2[k * C_ + c]);
    }
    return;
  }

  const int r0 = blockIdx.x * 2;
  __shared__ float fL[2][C_];
  __shared__ float xq[2][C_];
  __shared__ float xk[2][C_];
  __shared__ float red[8];

  #pragma unroll
  for (int r = 0; r < 2; ++r) fL[r][tid] = feat[(r0 + r) * C_ + tid];
  __syncthreads();

  // dist = (sum |feat| > 0)
  {
    float a = fabsf(fL[0][tid]), b = fabsf(fL[1][tid]);
    blockReduce2(a, b, red);
    if (tid == 0) { dist[r0 + 0] = a > 0.f ? 1.f : 0.f; dist[r0 + 1] = b > 0.f ? 1.f : 0.f; }
  }

  // q/k/v matmuls (fp32)
  float aq[2] = {0,0}, ak[2] = {0,0}, av[2] = {0,0};
  for (int cp = 0; cp < C_; ++cp) {
    float wq = Wq[cp * C_ + tid], wk = Wk[cp * C_ + tid], wv = Wv[cp * C_ + tid];
    #pragma unroll
    for (int r = 0; r < 2; ++r) {
      float f = fL[r][cp];
      aq[r] += f * wq; ak[r] += f * wk; av[r] += f * wv;
    }
  }
  {
    float bvv = bv[tid];
    #pragma unroll
    for (int r = 0; r < 2; ++r) vout[(r0 + r) * C_ + tid] = av[r] + bvv;
  }

  const float bqv = bq[tid], bkv = bk[tid];
  const float gqv = gq[tid], bgqv = bgq[tid], gkv = gk[tid], bgkv = bgk[tid];
  for (int r = 0; r < 2; ++r) {
    float qv = aq[r] + bqv, kv = ak[r] + bkv;
    float s1 = qv, s2 = qv * qv;
    blockReduce2(s1, s2, red);
    float mu = s1 * (1.f / C_);
    float rs = rsqrtf(s2 * (1.f / C_) - mu * mu + 1e-5f);
    xq[r][tid] = mish_f((qv - mu) * rs * gqv + bgqv);
    s1 = kv; s2 = kv * kv;
    blockReduce2(s1, s2, red);
    mu = s1 * (1.f / C_);
    rs = rsqrtf(s2 * (1.f / C_) - mu * mu + 1e-5f);
    xk[r][tid] = mish_f((kv - mu) * rs * gkv + bgkv);
  }
  __syncthreads();

  // Qp = q@W1, Kp = k@W1 + b1 (+ row stats, bf16 copies)
  float pq[2] = {0,0}, pk[2] = {0,0};
  for (int cp = 0; cp < C_; ++cp) {
    float w1 = W1[cp * C_ + tid];
    #pragma unroll
    for (int r = 0; r < 2; ++r) { pq[r] += xq[r][cp] * w1; pk[r] += xk[r][cp] * w1; }
  }
  const float b1v = b1[tid];
  for (int r = 0; r < 2; ++r) {
    float qv2 = pq[r];
    float kv2 = pk[r] + b1v;
    Qp[(r0 + r) * C_ + tid] = qv2;
    Kp[(r0 + r) * C_ + tid] = kv2;
    Qb[(r0 + r) * C_ + tid] = f2bf(qv2);
    Kb[(r0 + r) * C_ + tid] = f2bf(kv2);
    float s1 = qv2, s2 = qv2 * qv2;
    blockReduce2(s1, s2, red);
    if (tid == 0) { muQ[r0 + r] = s1 * (1.f / C_); s2Q[r0 + r] = s2; }
    s1 = kv2; s2 = kv2 * kv2;
    blockReduce2(s1, s2, red);
    if (tid == 0) { muK[r0 + r] = s1 * (1.f / C_); s2K[r0 + r] = s2; }
  }
}

// ---------------- G = Qp @ Kp^T (bf16 MFMA, fp32 out) - verified R2/R3 ----------------
__global__ void __launch_bounds__(256) gemmG_kernel(
    const unsigned short* __restrict__ Qb, const unsigned short* __restrict__ Kb,
    float* __restrict__ G) {
  const int tid = threadIdx.x;
  const int lane = tid & 63, wave = tid >> 6;
  const int bi = blockIdx.x >> 4, bj = blockIdx.x & 15;
  const int i0 = bi * 32 + (wave >> 1) * 16;
  const int j0 = bj * 32 + (wave & 1) * 16;
  const int jr = lane & 15, kg = lane >> 4;
  const unsigned short* qrow = Qb + (i0 + jr) * C_;
  const unsigned short* krow = Kb + (j0 + jr) * C_;
  f4v acc = (f4v){0.f, 0.f, 0.f, 0.f};
  #pragma unroll
  for (int ks = 0; ks < 8; ++ks) {
    const int kb = ks * 32 + kg * 4;
    s4v alo = *reinterpret_cast<const s4v*>(qrow + kb);
    s4v ahi = *reinterpret_cast<const s4v*>(qrow + kb + 16);
    s4v blo = *reinterpret_cast<const s4v*>(krow + kb);
    s4v bhi = *reinterpret_cast<const s4v*>(krow + kb + 16);
    s8v A, Bv;
    A[0]=alo[0];A[1]=alo[1];A[2]=alo[2];A[3]=alo[3];
    A[4]=ahi[0];A[5]=ahi[1];A[6]=ahi[2];A[7]=ahi[3];
    Bv[0]=blo[0];Bv[1]=blo[1];Bv[2]=blo[2];Bv[3]=blo[3];
    Bv[4]=bhi[0];Bv[5]=bhi[1];Bv[6]=bhi[2];Bv[7]=bhi[3];
    acc = __builtin_amdgcn_mfma_f32_16x16x32_bf16(A, Bv, acc, 0, 0, 0);
  }
  #pragma unroll
  for (int r = 0; r < 4; ++r)
    G[(i0 + kg * 4 + r) * N_ + j0 + jr] = acc[r];
}

// ---------------- main fused kernel (pass 1 of 2) ----------------
// grid (512, 2): blockIdx.x = i, blockIdx.y = j-chunk (256 j's). 512 thr = 8 waves.
// Per phase: tphase writes 64 rows (2 subtiles, R7-verified 32-row layout each)
// -> barrier -> {16 MFMA + softmax} x 2 subtiles (wv reused) -> barrier.
__global__ void __launch_bounds__(512, 4) attn_kernel(
    const float* __restrict__ dist, const float* __restrict__ v,
    const float* __restrict__ Qp, const float* __restrict__ Kp,
    const float* __restrict__ muQ, const float* __restrict__ s2Q,
    const float* __restrict__ muK, const float* __restrict__ s2K,
    const float* __restrict__ G, const unsigned short* __restrict__ W2f,
    const float* __restrict__ gw, const float* __restrict__ bw,
    float* __restrict__ pden, float* __restrict__ pacc) {
  const int tid = threadIdx.x;
  const int i = blockIdx.x;
  const int chunk = blockIdx.y;
  const int j0 = chunk * JPB;
  const int lane = tid & 63, wave = tid >> 6;
  const int jg = tid >> 4, g = tid & 15;   // tphase: 32 j-rows x 16 ch/thread per subtile
  const int row = lane & 31, hi = lane >> 5;
  const int cw = (wave << 5) + row;        // this lane's output channel

  // T: 2 subtiles, each the R7-verified layout:
  //   16B chunk (ks*2+hi)*32+row ; byte = chunk*16 ^ ((ks&7)<<6)
  __shared__ __align__(16) unsigned short T[2][32 * C_];  // 32 KiB
  __shared__ __align__(16) float qpP[80 * 4];    // stride-5 chunks (R8-verified)
  __shared__ __align__(16) float gbL[144 * 4];   // stride-9 chunks (R8-verified)
  __shared__ float muKL[JPB], s2KL[JPB], GL[JPB], distL[JPB];  // 4 KiB, preloaded

  // ---- one-shot coalesced preloads (R10-verified fix for Gram latency) ----
  if (tid < C_) {
    const int c = tid;
    qpP[(5 * (c >> 4) + ((c >> 2) & 3)) * 4 + (c & 3)] = Qp[i * C_ + c];
    const int pc = 9 * (c >> 4) + ((c & 15) >> 1);
    gbL[pc * 4 + (c & 1) * 2]     = gw[c];
    gbL[pc * 4 + (c & 1) * 2 + 1] = bw[c];
    muKL[tid] = muK[j0 + tid];
    s2KL[tid] = s2K[j0 + tid];
  } else {
    const int t = tid - C_;
    GL[t]    = G[i * N_ + j0 + t];
    distL[t] = dist[j0 + t];
  }

  // resident B fragments: 16 ksteps x 4 VGPR = 64 VGPR (32 channels/wave)
  s8v Bfr[16];
  #pragma unroll
  for (int ks = 0; ks < 16; ++ks)
    Bfr[ks] = *reinterpret_cast<const s8v*>(
        W2f + ((((wave << 4) + ks) * 64 + lane) << 3));

  const float muQ_i = muQ[i], s2Q_i = s2Q[i];

  float den = 0.f, accv = 0.f;
  __syncthreads();  // preloads ready

  // T write offsets for this thread (ks = g): hi=0 and hi=1 chunks (per subtile)
  const int swz = (g & 7) << 6;
  const int wb0 = (((((g << 1)    ) << 5) + jg) << 4) ^ swz;
  const int wb1 = (((((g << 1) + 1) << 5) + jg) << 4) ^ swz;
  const f4v* qp4 = reinterpret_cast<const f4v*>(qpP) + 5 * g;
  const f4v* gb4 = reinterpret_cast<const f4v*>(gbL) + 9 * g;

  for (int n = 0; n < NT; ++n) {
    // ---- T phase: rows n*64 + s*32 + jg, s = 0,1 (sequential, temps reused) ----
    #pragma unroll 1
    for (int s = 0; s < 2; ++s) {
      const int jj = n * JT + (s << 5) + jg;   // chunk-local j
      const float muj = muKL[jj] - muQ_i;
      const float ex2 = (s2KL[jj] + s2Q_i - 2.f * GL[jj]) * (1.f / C_);
      const float rs = rsqrtf(fmaxf(ex2 - muj * muj, 0.f) + 1e-5f);
      const float* kpr = Kp + (j0 + jj) * C_ + (g << 4);
      u4v p0, p1;
      #pragma unroll
      for (int m = 0; m < 4; ++m) {
        f4v kk = *reinterpret_cast<const f4v*>(kpr + (m << 2));
        f4v qq = qp4[m];                  // conflict-free b128
        f4v ga  = gb4[2 * m];             // {gw[c],bw[c],gw[c+1],bw[c+1]}
        f4v gb_ = gb4[2 * m + 1];
        #pragma unroll
        for (int h = 0; h < 2; ++h) {
          f4v gg = h ? gb_ : ga;
          float x0 = kk[2 * h]     - qq[2 * h]     - muj;
          float x1 = kk[2 * h + 1] - qq[2 * h + 1] - muj;
          float a  = mish_f(fmaf(x0, rs * gg[0], gg[1]));
          float b2 = mish_f(fmaf(x1, rs * gg[2], gg[3]));
          // cheap round-to-nearest bf16 (values finite)
          unsigned pa = (__float_as_uint(a) + 0x8000u) >> 16;
          unsigned pb = (__float_as_uint(b2) + 0x8000u) & 0xFFFF0000u;
          unsigned pk = pa | pb;
          if (m < 2) p0[m * 2 + h] = pk; else p1[(m - 2) * 2 + h] = pk;
        }
      }
      char* Tw = reinterpret_cast<char*>(T[s]);
      *reinterpret_cast<u4v*>(Tw + wb0) = p0;  // c = g*16+0..7   (ks=g, hi=0)
      *reinterpret_cast<u4v*>(Tw + wb1) = p1;  // c = g*16+8..15  (ks=g, hi=1)
    }
    __syncthreads();

    // ---- compute both subtiles between one barrier pair (wv reused) ----
    #pragma unroll 1
    for (int s = 0; s < 2; ++s) {
      const char* Tr = reinterpret_cast<const char*>(T[s]);
      f16v wv;
      #pragma unroll
      for (int r = 0; r < 16; ++r) wv[r] = 0.f;
      #pragma unroll
      for (int ks = 0; ks < 16; ++ks) {
        const int off = (((((ks << 1) + hi) << 5) + row) << 4) ^ ((ks & 7) << 6);
        s8v A = *reinterpret_cast<const s8v*>(Tr + off);
        wv = __builtin_amdgcn_mfma_f32_32x32x16_bf16(A, Bfr[ks], wv, 0, 0, 0);
      }
      // max-free softmax accumulate (D layout: col=lane&31,
      // row=(r&3)+8*(r>>2)+4*(lane>>5), verified m74/m101)
      const int jbase = n * JT + (s << 5);
      #pragma unroll
      for (int r = 0; r < 16; ++r) {
        const int jj = (r & 3) + ((r >> 2) << 3) + (hi << 2);
        float e = __expf(fminf(wv[r], 60.f)) * distL[jbase + jj];
        den += e;
        accv += e * v[(j0 + jbase + jj) * C_ + cw];
      }
    }
    __syncthreads();  // protect T before next phase's writes
  }

  // halves hold disjoint j-rows of the same channel: one xor-32 merge
  den  += __shfl_xor(den, 32);
  accv += __shfl_xor(accv, 32);
  if (lane < 32) {
    pden[(chunk * N_ + i) * C_ + cw] = den;
    pacc[(chunk * N_ + i) * C_ + cw] = accv;
  }
}

// ---------------- pass 2: merge chunk partials ----------------
__global__ void __launch_bounds__(256) reduce_kernel(
    const float* __restrict__ dist,
    const float* __restrict__ pden, const float* __restrict__ pacc,
    float* __restrict__ out) {
  const int i = blockIdx.x, c = threadIdx.x;
  float den = 0.f, acc = 0.f;
  #pragma unroll
  for (int ch = 0; ch < NCHUNK; ++ch) {
    den += pden[(ch * N_ + i) * C_ + c];
    acc += pacc[(ch * N_ + i) * C_ + c];
  }
  float o = 0.f;
  if (dist[i] > 0.f && den > 0.f) o = acc / den;
  out[i * C_ + c] = o;
}

extern "C" void kernel_launch(void* const* d_in, const int* in_sizes, int n_in,
                              void* d_out, int out_size, void* d_ws, size_t ws_size,
                              hipStream_t stream) {
  const float* feat = (const float*)d_in[0];
  const float* Wq   = (const float*)d_in[1];
  const float* bq   = (const float*)d_in[2];
  const float* gq   = (const float*)d_in[3];
  const float* bgq  = (const float*)d_in[4];
  const float* Wk   = (const float*)d_in[5];
  const float* bk   = (const float*)d_in[6];
  const float* gk   = (const float*)d_in[7];
  const float* bgk  = (const float*)d_in[8];
  const float* Wv   = (const float*)d_in[9];
  const float* bv   = (const float*)d_in[10];
  const float* W1   = (const float*)d_in[11];
  const float* b1   = (const float*)d_in[12];
  const float* gw   = (const float*)d_in[13];
  const float* bw   = (const float*)d_in[14];
  const float* W2   = (const float*)d_in[15];
  // d_in[16] = b2 : cancels exactly in the j-softmax, unused.

  char* ws = (char*)d_ws;
  float* dist = (float*)(ws + 0);            // 512 f32
  float* muQ  = (float*)(ws + 2048);
  float* s2Q  = (float*)(ws + 4096);
  float* muK  = (float*)(ws + 6144);
  float* s2K  = (float*)(ws + 8192);
  float* v    = (float*)(ws + 0x010000);     // 512 KB
  float* Qp   = (float*)(ws + 0x090000);     // 512 KB
  float* Kp   = (float*)(ws + 0x110000);     // 512 KB
  unsigned short* Qb  = (unsigned short*)(ws + 0x190000);  // 256 KB
  unsigned short* Kb  = (unsigned short*)(ws + 0x1D0000);  // 256 KB
  unsigned short* W2f = (unsigned short*)(ws + 0x210000);  // 128 KB
  float* G    = (float*)(ws + 0x230000);     // 1 MB
  float* pden = (float*)(ws + 0x330000);     // 1 MB
  float* pacc = (float*)(ws + 0x430000);     // 1 MB

  hipLaunchKernelGGL(prep_kernel, dim3(512), dim3(256), 0, stream,
                     feat, Wq, bq, gq, bgq, Wk, bk, gk, bgk, Wv, bv, W1, b1,
                     W2, W2f, dist, v, Qp, Kp, muQ, s2Q, muK, s2K, Qb, Kb);
  hipLaunchKernelGGL(gemmG_kernel, dim3(256), dim3(256), 0, stream, Qb, Kb, G);
  hipLaunchKernelGGL(attn_kernel, dim3(512, NCHUNK), dim3(512), 0, stream,
                     dist, v, Qp, Kp, muQ, s2Q, muK, s2K, G, W2f, gw, bw,
                     pden, pacc);
  hipLaunchKernelGGL(reduce_kernel, dim3(512), dim3(256), 0, stream,
                     dist, pden, pacc, (float*)d_out);
}

// Round 17
// 120.755 us; speedup vs baseline: 1.4433x; 1.4433x over previous
//
#include <hip/hip_runtime.h>
#include <hip/hip_bf16.h>
#include <math.h>

// Problem: B=1, N=512, C=256, fp32 in/out.
// out[i,c] = sum_j softmax_j( w[i,j,c] ) * v[j,c],  w = mish(LN(Kp[j]-Qp[i])) @ W2  (+b2 cancels)
// Kp = mish(LN(feat@Wk+bk)) @ W1 + b1 ; Qp = mish(LN(feat@Wq+bq)) @ W1 ; v = feat@Wv+bv
// R17 = attn from R13/R15 EXACT (verified 3x at ~103us; every widening of the
//       inter-barrier region spills: R2/R11/R14/R16) + prep with fused repack
//       (R16's safe half: independent blocks, saves one launch).

#define N_ 512
#define C_ 256
#define NCHUNK 2
#define JPB (N_ / NCHUNK)   // 256 j's per block
#define JT 32               // j rows per tile

typedef short s8v __attribute__((ext_vector_type(8)));
typedef short s4v __attribute__((ext_vector_type(4)));
typedef float f4v __attribute__((ext_vector_type(4)));
typedef float f16v __attribute__((ext_vector_type(16)));
typedef unsigned int u4v __attribute__((ext_vector_type(4)));

__device__ __forceinline__ unsigned short f2bf(float x) {
  union { __hip_bfloat16 h; unsigned short u; } cv;
  cv.h = __float2bfloat16(x);
  return cv.u;
}

__device__ __forceinline__ float mish_f(float x) {
  // mish(x) = x*tanh(softplus(x)) = x*(1 - 2/(y^2+1)), y = 1+e^x
  if (x > 25.f) return x;  // tanh saturated to 1.0 in fp32
  float y = 1.f + __expf(x);
  return x - __fdividef(x + x, fmaf(y, y, 1.f));
}

// block (256 thr) reduction of two values, result broadcast to all threads
__device__ __forceinline__ void blockReduce2(float& a, float& b, float* red) {
  #pragma unroll
  for (int m = 1; m < 64; m <<= 1) { a += __shfl_xor(a, m); b += __shfl_xor(b, m); }
  int lane = threadIdx.x & 63, w = threadIdx.x >> 6;
  if (lane == 0) { red[w] = a; red[4 + w] = b; }
  __syncthreads();
  a = red[0] + red[1] + red[2] + red[3];
  b = red[4] + red[5] + red[6] + red[7];
  __syncthreads();
}

// ---------------- prep (blocks 0..255): dist, v, Qp, Kp, stats, bf16 copies
// ---------------- repack (blocks 256..511): W2 -> W2f fragment-linear ----------------
__global__ void __launch_bounds__(256) prep_kernel(
    const float* __restrict__ feat,
    const float* __restrict__ Wq, const float* __restrict__ bq,
    const float* __restrict__ gq, const float* __restrict__ bgq,
    const float* __restrict__ Wk, const float* __restrict__ bk,
    const float* __restrict__ gk, const float* __restrict__ bgk,
    const float* __restrict__ Wv, const float* __restrict__ bv,
    const float* __restrict__ W1, const float* __restrict__ b1,
    const float* __restrict__ W2, unsigned short* __restrict__ W2f,
    float* __restrict__ dist, float* __restrict__ vout,
    float* __restrict__ Qp, float* __restrict__ Kp,
    float* __restrict__ muQ, float* __restrict__ s2Q,
    float* __restrict__ muK, float* __restrict__ s2K,
    unsigned short* __restrict__ Qb, unsigned short* __restrict__ Kb) {
  const int tid = threadIdx.x;

  if (blockIdx.x >= 256) {
    // repack: W2f[((w*16+ks)*64+l)*8+e] = bf16(W2[k][c]),
    //   k = ks*16 + (l>>5)*8 + e, c = w*32 + (l&31)
    // 256 blocks x 256 threads = 65536 = one element per thread.
    int idx = (blockIdx.x - 256) * 256 + tid;
    int e = idx & 7;
    int l = (idx >> 3) & 63;
    int ks = (idx >> 9) & 15;
    int w = idx >> 13;
    int k = ks * 16 + ((l >> 5) << 3) + e;
    int c = (w << 5) + (l & 31);
    W2f[idx] = f2bf(W2[k * C_ + c]);
    return;
  }

  const int r0 = blockIdx.x * 2;
  __shared__ float fL[2][C_];
  __shared__ float xq[2][C_];
  __shared__ float xk[2][C_];
  __shared__ float red[8];

  #pragma unroll
  for (int r = 0; r < 2; ++r) fL[r][tid] = feat[(r0 + r) * C_ + tid];
  __syncthreads();

  // dist = (sum |feat| > 0)
  {
    float a = fabsf(fL[0][tid]), b = fabsf(fL[1][tid]);
    blockReduce2(a, b, red);
    if (tid == 0) { dist[r0 + 0] = a > 0.f ? 1.f : 0.f; dist[r0 + 1] = b > 0.f ? 1.f : 0.f; }
  }

  // q/k/v matmuls (fp32)
  float aq[2] = {0,0}, ak[2] = {0,0}, av[2] = {0,0};
  for (int cp = 0; cp < C_; ++cp) {
    float wq = Wq[cp * C_ + tid], wk = Wk[cp * C_ + tid], wv = Wv[cp * C_ + tid];
    #pragma unroll
    for (int r = 0; r < 2; ++r) {
      float f = fL[r][cp];
      aq[r] += f * wq; ak[r] += f * wk; av[r] += f * wv;
    }
  }
  {
    float bvv = bv[tid];
    #pragma unroll
    for (int r = 0; r < 2; ++r) vout[(r0 + r) * C_ + tid] = av[r] + bvv;
  }

  const float bqv = bq[tid], bkv = bk[tid];
  const float gqv = gq[tid], bgqv = bgq[tid], gkv = gk[tid], bgkv = bgk[tid];
  for (int r = 0; r < 2; ++r) {
    float qv = aq[r] + bqv, kv = ak[r] + bkv;
    float s1 = qv, s2 = qv * qv;
    blockReduce2(s1, s2, red);
    float mu = s1 * (1.f / C_);
    float rs = rsqrtf(s2 * (1.f / C_) - mu * mu + 1e-5f);
    xq[r][tid] = mish_f((qv - mu) * rs * gqv + bgqv);
    s1 = kv; s2 = kv * kv;
    blockReduce2(s1, s2, red);
    mu = s1 * (1.f / C_);
    rs = rsqrtf(s2 * (1.f / C_) - mu * mu + 1e-5f);
    xk[r][tid] = mish_f((kv - mu) * rs * gkv + bgkv);
  }
  __syncthreads();

  // Qp = q@W1, Kp = k@W1 + b1 (+ row stats, bf16 copies)
  float pq[2] = {0,0}, pk[2] = {0,0};
  for (int cp = 0; cp < C_; ++cp) {
    float w1 = W1[cp * C_ + tid];
    #pragma unroll
    for (int r = 0; r < 2; ++r) { pq[r] += xq[r][cp] * w1; pk[r] += xk[r][cp] * w1; }
  }
  const float b1v = b1[tid];
  for (int r = 0; r < 2; ++r) {
    float qv2 = pq[r];
    float kv2 = pk[r] + b1v;
    Qp[(r0 + r) * C_ + tid] = qv2;
    Kp[(r0 + r) * C_ + tid] = kv2;
    Qb[(r0 + r) * C_ + tid] = f2bf(qv2);
    Kb[(r0 + r) * C_ + tid] = f2bf(kv2);
    float s1 = qv2, s2 = qv2 * qv2;
    blockReduce2(s1, s2, red);
    if (tid == 0) { muQ[r0 + r] = s1 * (1.f / C_); s2Q[r0 + r] = s2; }
    s1 = kv2; s2 = kv2 * kv2;
    blockReduce2(s1, s2, red);
    if (tid == 0) { muK[r0 + r] = s1 * (1.f / C_); s2K[r0 + r] = s2; }
  }
}

// ---------------- G = Qp @ Kp^T (bf16 MFMA, fp32 out) - verified R2/R3 ----------------
__global__ void __launch_bounds__(256) gemmG_kernel(
    const unsigned short* __restrict__ Qb, const unsigned short* __restrict__ Kb,
    float* __restrict__ G) {
  const int tid = threadIdx.x;
  const int lane = tid & 63, wave = tid >> 6;
  const int bi = blockIdx.x >> 4, bj = blockIdx.x & 15;
  const int i0 = bi * 32 + (wave >> 1) * 16;
  const int j0 = bj * 32 + (wave & 1) * 16;
  const int jr = lane & 15, kg = lane >> 4;
  const unsigned short* qrow = Qb + (i0 + jr) * C_;
  const unsigned short* krow = Kb + (j0 + jr) * C_;
  f4v acc = (f4v){0.f, 0.f, 0.f, 0.f};
  #pragma unroll
  for (int ks = 0; ks < 8; ++ks) {
    const int kb = ks * 32 + kg * 4;
    s4v alo = *reinterpret_cast<const s4v*>(qrow + kb);
    s4v ahi = *reinterpret_cast<const s4v*>(qrow + kb + 16);
    s4v blo = *reinterpret_cast<const s4v*>(krow + kb);
    s4v bhi = *reinterpret_cast<const s4v*>(krow + kb + 16);
    s8v A, Bv;
    A[0]=alo[0];A[1]=alo[1];A[2]=alo[2];A[3]=alo[3];
    A[4]=ahi[0];A[5]=ahi[1];A[6]=ahi[2];A[7]=ahi[3];
    Bv[0]=blo[0];Bv[1]=blo[1];Bv[2]=blo[2];Bv[3]=blo[3];
    Bv[4]=bhi[0];Bv[5]=bhi[1];Bv[6]=bhi[2];Bv[7]=bhi[3];
    acc = __builtin_amdgcn_mfma_f32_16x16x32_bf16(A, Bv, acc, 0, 0, 0);
  }
  #pragma unroll
  for (int r = 0; r < 4; ++r)
    G[(i0 + kg * 4 + r) * N_ + j0 + jr] = acc[r];
}

// ---------------- main fused kernel (pass 1 of 2) - R13/R15 EXACT ----------------
// grid (512, 2): blockIdx.x = i, blockIdx.y = j-chunk (256 j's). 512 thr = 8 waves.
__global__ void __launch_bounds__(512, 4) attn_kernel(
    const float* __restrict__ dist, const float* __restrict__ v,
    const float* __restrict__ Qp, const float* __restrict__ Kp,
    const float* __restrict__ muQ, const float* __restrict__ s2Q,
    const float* __restrict__ muK, const float* __restrict__ s2K,
    const float* __restrict__ G, const unsigned short* __restrict__ W2f,
    const float* __restrict__ gw, const float* __restrict__ bw,
    float* __restrict__ pden, float* __restrict__ pacc) {
  const int tid = threadIdx.x;
  const int i = blockIdx.x;
  const int chunk = blockIdx.y;
  const int j0 = chunk * JPB;
  const int lane = tid & 63, wave = tid >> 6;
  const int jg = tid >> 4, g = tid & 15;   // tphase: 32 j-rows x 16 ch/thread
  const int row = lane & 31, hi = lane >> 5;
  const int cw = (wave << 5) + row;        // this lane's output channel

  // T layout: 16B chunk index (ks*2+hi)*32 + row ; byte = chunk*16 ^ ((ks&7)<<6)
  __shared__ __align__(16) unsigned short T[JT * C_];  // 16 KiB
  __shared__ __align__(16) float qpP[80 * 4];    // stride-5 chunks (R8-verified)
  __shared__ __align__(16) float gbL[144 * 4];   // stride-9 chunks (R8-verified)
  __shared__ float muKL[JPB], s2KL[JPB], GL[JPB], distL[JPB];  // 4 KiB, preloaded
  char* Tb = reinterpret_cast<char*>(T);

  // ---- one-shot coalesced preloads (R10-verified fix for Gram latency) ----
  if (tid < C_) {
    const int c = tid;
    qpP[(5 * (c >> 4) + ((c >> 2) & 3)) * 4 + (c & 3)] = Qp[i * C_ + c];
    const int pc = 9 * (c >> 4) + ((c & 15) >> 1);
    gbL[pc * 4 + (c & 1) * 2]     = gw[c];
    gbL[pc * 4 + (c & 1) * 2 + 1] = bw[c];
    muKL[tid] = muK[j0 + tid];
    s2KL[tid] = s2K[j0 + tid];
  } else {
    const int t = tid - C_;
    GL[t]    = G[i * N_ + j0 + t];
    distL[t] = dist[j0 + t];
  }

  // resident B fragments: 16 ksteps x 4 VGPR = 64 VGPR (32 channels/wave)
  s8v Bfr[16];
  #pragma unroll
  for (int ks = 0; ks < 16; ++ks)
    Bfr[ks] = *reinterpret_cast<const s8v*>(
        W2f + ((((wave << 4) + ks) * 64 + lane) << 3));

  const float muQ_i = muQ[i], s2Q_i = s2Q[i];

  float den = 0.f, accv = 0.f;
  __syncthreads();  // preloads ready

  // T write offsets for this thread (ks = g): hi=0 and hi=1 chunks
  const int swz = (g & 7) << 6;
  const int wb0 = (((((g << 1)    ) << 5) + jg) << 4) ^ swz;
  const int wb1 = (((((g << 1) + 1) << 5) + jg) << 4) ^ swz;
  const f4v* qp4 = reinterpret_cast<const f4v*>(qpP) + 5 * g;
  const f4v* gb4 = reinterpret_cast<const f4v*>(gbL) + 9 * g;

  for (int jt = 0; jt < JPB / JT; ++jt) {
    const int jb = j0 + jt * JT;
    // ---- T phase: t[j, g*16..+15] = mish(LN(Kp[j]-Qp[i])), stats from LDS ----
    {
      const int jj = jt * JT + jg;     // chunk-local j
      const float muj = muKL[jj] - muQ_i;
      const float ex2 = (s2KL[jj] + s2Q_i - 2.f * GL[jj]) * (1.f / C_);
      const float rs = rsqrtf(fmaxf(ex2 - muj * muj, 0.f) + 1e-5f);
      const float* kpr = Kp + (j0 + jj) * C_ + (g << 4);
      u4v p0, p1;
      #pragma unroll
      for (int m = 0; m < 4; ++m) {
        f4v kk = *reinterpret_cast<const f4v*>(kpr + (m << 2));
        f4v qq = qp4[m];                  // conflict-free b128
        f4v ga  = gb4[2 * m];             // {gw[c],bw[c],gw[c+1],bw[c+1]}
        f4v gb_ = gb4[2 * m + 1];
        #pragma unroll
        for (int h = 0; h < 2; ++h) {
          f4v gg = h ? gb_ : ga;
          float x0 = kk[2 * h]     - qq[2 * h]     - muj;
          float x1 = kk[2 * h + 1] - qq[2 * h + 1] - muj;
          float a  = mish_f(fmaf(x0, rs * gg[0], gg[1]));
          float b2 = mish_f(fmaf(x1, rs * gg[2], gg[3]));
          // cheap round-to-nearest bf16 (values finite)
          unsigned pa = (__float_as_uint(a) + 0x8000u) >> 16;
          unsigned pb = (__float_as_uint(b2) + 0x8000u) & 0xFFFF0000u;
          unsigned pk = pa | pb;
          if (m < 2) p0[m * 2 + h] = pk; else p1[(m - 2) * 2 + h] = pk;
        }
      }
      *reinterpret_cast<u4v*>(Tb + wb0) = p0;  // c = g*16+0..7   (ks=g, hi=0)
      *reinterpret_cast<u4v*>(Tb + wb1) = p1;  // c = g*16+8..15  (ks=g, hi=1)
    }
    __syncthreads();

    // ---- MFMA: w[32 x 256] = T @ W2 ; this wave: channels wave*32..+31 ----
    f16v wv;
    #pragma unroll
    for (int r = 0; r < 16; ++r) wv[r] = 0.f;
    #pragma unroll
    for (int ks = 0; ks < 16; ++ks) {
      const int off = (((((ks << 1) + hi) << 5) + row) << 4) ^ ((ks & 7) << 6);
      s8v A = *reinterpret_cast<const s8v*>(Tb + off);
      wv = __builtin_amdgcn_mfma_f32_32x32x16_bf16(A, Bfr[ks], wv, 0, 0, 0);
    }

    // ---- max-free softmax accumulate (D layout: col=lane&31,
    //      row=(r&3)+8*(r>>2)+4*(lane>>5), verified m74/m101) ----
    #pragma unroll
    for (int r = 0; r < 16; ++r) {
      const int jj = (r & 3) + ((r >> 2) << 3) + (hi << 2);
      float e = __expf(fminf(wv[r], 60.f)) * distL[jt * JT + jj];
      den += e;
      accv += e * v[(jb + jj) * C_ + cw];
    }
    __syncthreads();  // protect T before next tile's writes
  }

  // halves hold disjoint j-rows of the same channel: one xor-32 merge
  den  += __shfl_xor(den, 32);
  accv += __shfl_xor(accv, 32);
  if (lane < 32) {
    pden[(chunk * N_ + i) * C_ + cw] = den;
    pacc[(chunk * N_ + i) * C_ + cw] = accv;
  }
}

// ---------------- pass 2: merge chunk partials ----------------
__global__ void __launch_bounds__(256) reduce_kernel(
    const float* __restrict__ dist,
    const float* __restrict__ pden, const float* __restrict__ pacc,
    float* __restrict__ out) {
  const int i = blockIdx.x, c = threadIdx.x;
  float den = 0.f, acc = 0.f;
  #pragma unroll
  for (int ch = 0; ch < NCHUNK; ++ch) {
    den += pden[(ch * N_ + i) * C_ + c];
    acc += pacc[(ch * N_ + i) * C_ + c];
  }
  float o = 0.f;
  if (dist[i] > 0.f && den > 0.f) o = acc / den;
  out[i * C_ + c] = o;
}

extern "C" void kernel_launch(void* const* d_in, const int* in_sizes, int n_in,
                              void* d_out, int out_size, void* d_ws, size_t ws_size,
                              hipStream_t stream) {
  const float* feat = (const float*)d_in[0];
  const float* Wq   = (const float*)d_in[1];
  const float* bq   = (const float*)d_in[2];
  const float* gq   = (const float*)d_in[3];
  const float* bgq  = (const float*)d_in[4];
  const float* Wk   = (const float*)d_in[5];
  const float* bk   = (const float*)d_in[6];
  const float* gk   = (const float*)d_in[7];
  const float* bgk  = (const float*)d_in[8];
  const float* Wv   = (const float*)d_in[9];
  const float* bv   = (const float*)d_in[10];
  const float* W1   = (const float*)d_in[11];
  const float* b1   = (const float*)d_in[12];
  const float* gw   = (const float*)d_in[13];
  const float* bw   = (const float*)d_in[14];
  const float* W2   = (const float*)d_in[15];
  // d_in[16] = b2 : cancels exactly in the j-softmax, unused.

  char* ws = (char*)d_ws;
  float* dist = (float*)(ws + 0);            // 512 f32
  float* muQ  = (float*)(ws + 2048);
  float* s2Q  = (float*)(ws + 4096);
  float* muK  = (float*)(ws + 6144);
  float* s2K  = (float*)(ws + 8192);
  float* v    = (float*)(ws + 0x010000);     // 512 KB
  float* Qp   = (float*)(ws + 0x090000);     // 512 KB
  float* Kp   = (float*)(ws + 0x110000);     // 512 KB
  unsigned short* Qb  = (unsigned short*)(ws + 0x190000);  // 256 KB
  unsigned short* Kb  = (unsigned short*)(ws + 0x1D0000);  // 256 KB
  unsigned short* W2f = (unsigned short*)(ws + 0x210000);  // 128 KB
  float* G    = (float*)(ws + 0x230000);     // 1 MB
  float* pden = (float*)(ws + 0x330000);     // 1 MB
  float* pacc = (float*)(ws + 0x430000);     // 1 MB

  hipLaunchKernelGGL(prep_kernel, dim3(512), dim3(256), 0, stream,
                     feat, Wq, bq, gq, bgq, Wk, bk, gk, bgk, Wv, bv, W1, b1,
                     W2, W2f, dist, v, Qp, Kp, muQ, s2Q, muK, s2K, Qb, Kb);
  hipLaunchKernelGGL(gemmG_kernel, dim3(256), dim3(256), 0, stream, Qb, Kb, G);
  hipLaunchKernelGGL(attn_kernel, dim3(512, NCHUNK), dim3(512), 0, stream,
                     dist, v, Qp, Kp, muQ, s2Q, muK, s2K, G, W2f, gw, bw,
                     pden, pacc);
  hipLaunchKernelGGL(reduce_kernel, dim3(512), dim3(256), 0, stream,
                     dist, pden, pacc, (float*)d_out);
}